// Round 4
// baseline (105.473 us; speedup 1.0000x reference)
//
#include <hip/hip_runtime.h>

#define WG 256
#define G64 64     // num_graphs (fixed by problem)
#define SPLITS 16  // edge-chunks / node-subranges per graph
#define TILE 1024  // edges scanned per queue-drain round (overflow-proof cap)

// ---------------------------------------------------------------------------
// Single fused kernel. Grid (G64, SPLITS), 256 threads.
// batch is SORTED -> edge membership in graph g is a pure range test on the
// source node index: n0(g) <= src < n1(g). So no counting sort, no cursor,
// no workspace: each block filters its edge chunk on the fly into an LDS
// queue (tiled drains, adversarial-proof) and runs the proven register
// clamped-linear accumulation.
// ---------------------------------------------------------------------------

__device__ __forceinline__ int lbound_par(const int* __restrict__ batch, int N,
                                          int val, int tid, int* scratch) {
    // 2-level parallel lower_bound: first index with batch[idx] >= val.
    const int stride = (N + WG - 1) / WG;
    if (tid == 0) *scratch = N;
    __syncthreads();
    int i0 = tid * stride;
    if (i0 < N && batch[i0] >= val) atomicMin(scratch, i0);
    __syncthreads();
    int hi = *scratch;                 // first qualifying probe point (or N)
    __syncthreads();
    if (tid == 0) *scratch = hi;
    __syncthreads();
    int lo = hi - stride + 1; if (lo < 0) lo = 0;
    int j = lo + tid;
    if (j < hi && batch[j] >= val) atomicMin(scratch, j);
    __syncthreads();
    int r = *scratch;
    __syncthreads();
    return r;
}

__global__ __launch_bounds__(WG) void k_fused(const float* __restrict__ x,
                                              const float* __restrict__ v,
                                              const float* __restrict__ lin,
                                              const int* __restrict__ edge,
                                              const int* __restrict__ batch,
                                              float* __restrict__ out,
                                              int E, int N) {
    __shared__ int2  queue[TILE];      // matched (src,dst) of current tile
    __shared__ float stage[4 * 1024];  // flush staging (also after acc loops)
    __shared__ int   qn, scratch;

    int g = blockIdx.x, split = blockIdx.y;
    int tid = threadIdx.x, t = tid & 31, sub = tid >> 5;

    // node range of graph g via sorted batch
    int n0 = lbound_par(batch, N, g,     tid, &scratch);
    int n1 = lbound_par(batch, N, g + 1, tid, &scratch);
    if (tid == 0) qn = 0;

    float v0 = v[t], v1 = v[32 + t], v2 = v[64 + t];
    float lin0 = lin[0];
    float dlin = lin[1] - lin[0];                 // > 0
    const float LOG2E = 1.4426950408889634f;
    float d2 = 200.f * dlin * LOG2E;              // exp-step in log2 units (~20.5)
    float inv_dlin = 1.f / dlin;
    float fstep = exp2f(-d2);                     // e-ratio per threshold (6.8e-7)

    float acc[32];
#pragma unroll
    for (int b = 0; b < 32; ++b) acc[b] = 0.f;

    // ---- node items (+): this split's subrange of [n0, n1), one per half-wave
    int nn = n1 - n0;
    int a0 = n0 + (int)((long long)nn * split / SPLITS);
    int a1 = n0 + (int)((long long)nn * (split + 1) / SPLITS);
    for (int idx = a0 + sub; idx < a1; idx += 8) {
        const float* xr = x + (size_t)idx * 3;
        float h = xr[0] * v0 + xr[1] * v1 + xr[2] * v2;
        float bs = (h - lin0) * inv_dlin;         // b* where sigmoid = 0.5
        float bF = floorf(bs);
        float e0 = exp2f((bs - bF) * d2);         // in [1, 2^20.5)
        float s0 = __builtin_amdgcn_rcpf(1.f + e0);             // sigmoid @ bF
        float s1 = __builtin_amdgcn_rcpf(fmaf(e0, fstep, 1.f)); // sigmoid @ bF+1
        float m = s1 - s0;
        float base = fmaf(-bF, m, s0);
#pragma unroll
        for (int b = 0; b < 32; ++b)
            acc[b] += __builtin_amdgcn_fmed3f(fmaf(m, (float)b, base), 0.f, 1.f);
    }

    // ---- edge items (-): scan chunk `split`, filter src in [n0,n1), drain ----
    int c0 = (int)((long long)E * split / SPLITS);
    int c1 = (int)((long long)E * (split + 1) / SPLITS);
    __syncthreads();  // qn=0 visible; queue reuse safe
    for (int ts = c0; ts < c1; ts += TILE) {
        int te = ts + TILE; if (te > c1) te = c1;
        // scan-push (coalesced src/dst loads; matches ~1.5% of scanned)
        for (int i = ts + tid; i < te; i += WG) {
            int s = edge[i];
            if (s >= n0 && s < n1) {
                int k = atomicAdd(&qn, 1);
                queue[k] = make_int2(s, edge[E + i]);
            }
        }
        __syncthreads();
        int q = qn;
        // process queue: one item per half-wave (LDS broadcast read)
        for (int k = sub; k < q; k += 8) {
            int2 sd = queue[k];
            const float* xs = x + (size_t)sd.x * 3;
            const float* xd = x + (size_t)sd.y * 3;
            float hs = xs[0] * v0 + xs[1] * v1 + xs[2] * v2;
            float hd = xd[0] * v0 + xd[1] * v1 + xd[2] * v2;
            float h = fmaxf(hs, hd);
            float bs = (h - lin0) * inv_dlin;
            float bF = floorf(bs);
            float e0 = exp2f((bs - bF) * d2);
            float s0 = __builtin_amdgcn_rcpf(1.f + e0);
            float s1 = __builtin_amdgcn_rcpf(fmaf(e0, fstep, 1.f));
            float m = -(s1 - s0);                 // sign folded into slope
            float base = fmaf(-bF, m, -s0);       // -(s0 - bF*(s1-s0))
#pragma unroll
            for (int b = 0; b < 32; ++b)
                acc[b] += __builtin_amdgcn_fmed3f(fmaf(m, (float)b, base), -1.f, 0.f);
        }
        __syncthreads();
        if (tid == 0) qn = 0;
        __syncthreads();
    }

    // --- block reduce + flush: shfl halves -> LDS stage[4][32b][32t] -> atomics
#pragma unroll
    for (int b = 0; b < 32; ++b) acc[b] += __shfl_xor(acc[b], 32, 64);
    int w = tid >> 6;
    if ((tid & 32) == 0) {
#pragma unroll
        for (int b = 0; b < 32; ++b) stage[(w << 10) + (b << 5) + t] = acc[b];
    }
    __syncthreads();
    for (int c = tid; c < 1024; c += WG) {
        float s = stage[c] + stage[1024 + c] + stage[2048 + c] + stage[3072 + c];
        unsafeAtomicAdd(&out[((size_t)g << 10) + c], s);
    }
}

extern "C" void kernel_launch(void* const* d_in, const int* in_sizes, int n_in,
                              void* d_out, int out_size, void* d_ws, size_t ws_size,
                              hipStream_t stream) {
    const float* x     = (const float*)d_in[0];
    const float* v     = (const float*)d_in[1];
    const float* lin   = (const float*)d_in[2];
    const int*   edge  = (const int*)d_in[3];
    const int*   batch = (const int*)d_in[4];
    int N = in_sizes[4];
    int E = in_sizes[3] / 2;
    (void)d_ws; (void)ws_size; (void)n_in;   // workspace unused

    float* out = (float*)d_out;
    hipMemsetAsync(out, 0, (size_t)out_size * sizeof(float), stream);

    dim3 grid(G64, SPLITS);
    k_fused<<<grid, WG, 0, stream>>>(x, v, lin, edge, batch, out, E, N);
}

// Round 5
// 90.807 us; speedup vs baseline: 1.1615x; 1.1615x over previous
//
#include <hip/hip_runtime.h>

#define WG 256
#define G64 64       // num_graphs (fixed by problem)
#define SPLITS 16    // blocks per graph in k_acc
#define SCALEI 1048576        // 2^20 fixed-point for sigmoid quantization
#define ISCALE 9.5367431640625e-07f   // 1/2^20

// ---------------------------------------------------------------------------
// k_bucket (proven R3 structure): one thread per edge. g = batch[src];
// block-aggregated cursor bump (64 global atomics per block); stores the int2
// endpoint indices at the claimed slot (x is 600 KB -> L2-resident, k_acc
// gathers coords itself). Blocks 0..63 zero out[g]'s 4 KB slab (replaces the
// memset(out) dispatch). Block 0 computes node_off = lower_bound(batch, g).
// ---------------------------------------------------------------------------
__global__ __launch_bounds__(WG) void k_bucket(const int* __restrict__ edge,
                                               const int* __restrict__ batch,
                                               int2* __restrict__ bucket,
                                               int* __restrict__ cursor,
                                               int* __restrict__ node_off,
                                               float* __restrict__ out,
                                               int E, int N, int CAP) {
    __shared__ int lc[G64], lb[G64];
    int tid = threadIdx.x;
    int bid = blockIdx.x;
    if (tid < G64) lc[tid] = 0;

    if (bid < G64) {  // zero this graph's output slab (1024 floats)
        float4* o4 = (float4*)(out + ((size_t)bid << 10));
        o4[tid] = make_float4(0.f, 0.f, 0.f, 0.f);
    }
    __syncthreads();

    int e = bid * WG + tid;
    int g = 0, r = 0, s = 0, d = 0;
    if (e < E) {
        s = edge[e];
        d = edge[E + e];
        g = batch[s];
        r = atomicAdd(&lc[g], 1);
    }
    __syncthreads();
    if (tid < G64 && lc[tid]) lb[tid] = atomicAdd(&cursor[tid], lc[tid]);
    __syncthreads();
    if (e < E) {
        int pos = lb[g] + r;
        if (pos < CAP) bucket[(size_t)g * CAP + pos] = make_int2(s, d);
    }

    if (bid == 0 && tid <= G64) {
        int lo = 0, hi = N;
        while (lo < hi) {
            int mid = (lo + hi) >> 1;
            if (batch[mid] < tid) lo = mid + 1; else hi = mid;
        }
        node_off[tid] = lo;
    }
}

// ---------------------------------------------------------------------------
// k_acc: block (g, split). INTEGER delta-histogram in LDS.
// The clamped-linear sigmoid profile over the 32 thresholds is a step
// function with exactly 3 non-zero deltas per item:
//   d[ib]   = s0        (true sigmoid at bF,   1/(1+e0))
//   d[ib+1] = s1 - s0   (true sigmoid at bF+1, 1/(1+e0*fstep))
//   d[ib+2] = 1 - s1
// Quantized to 2^20 fixed point they telescope exactly to SCALEI, so slot
// clamping into [0,33] (33 = dump row) reproduces exact 0/1 saturation.
// KEY: int LDS atomicAdd is native ds_add_u32 (float LDS atomicAdd is a CAS
// loop — it serialized 7x in R2; never use it). Addresses slot*32+t hit 32
// distinct banks per half-wave, 2-way across the wave = free (m136).
// Per item-lane: ~18 VALU + 1 exp2 + 2 rcp + 3 ds_add, vs ~110 VALU for the
// register b-loop. The block-wide histogram also replaces the 4-wave shfl +
// 16 KB stage reduction. Overflow headroom: <=~200 items/block * 2^20 =
// 2.1e8 << 2^31. Epilogue: 32-lane prefix over b, scale, 1024 atomics.
// ---------------------------------------------------------------------------
__global__ __launch_bounds__(WG) void k_acc(const float* __restrict__ x,
                                            const float* __restrict__ v,
                                            const int2* __restrict__ bucket,
                                            const float* __restrict__ lin,
                                            const int* __restrict__ cursor,
                                            const int* __restrict__ node_off,
                                            float* __restrict__ out, int CAP) {
    __shared__ int   hist[34 * 32];   // [delta-slot 0..33][t]
    __shared__ float colf[32 * 32];   // prefixed float result
    int tid = threadIdx.x;
    for (int i = tid; i < 34 * 32; i += WG) hist[i] = 0;

    int g = blockIdx.x;
    int n0 = node_off[g], n1 = node_off[g + 1];
    int nn = n1 - n0;
    int ne = cursor[g]; if (ne > CAP) ne = CAP;
    int L = nn + ne;
    int ipc = (L + SPLITS - 1) / SPLITS;
    int lo = blockIdx.y * ipc;
    int hi = lo + ipc; if (hi > L) hi = L;

    int t = tid & 31, sub = tid >> 5;
    float v0 = v[t], v1 = v[32 + t], v2 = v[64 + t];

    float lin0 = lin[0];
    float dlin = lin[1] - lin[0];                 // > 0
    const float LOG2E = 1.4426950408889634f;
    float d2 = 200.f * dlin * LOG2E;              // exp-step in log2 units (~20.5)
    float inv_dlin = 1.f / dlin;
    float fstep = exp2f(-d2);                     // e-ratio per threshold (6.8e-7)
    __syncthreads();

    // ---- node items (+): heights from contiguous x rows ----
    int nhi = hi < nn ? hi : nn;
    for (int idx = lo + sub; idx < nhi; idx += 8) {
        const float* xr = x + (size_t)(n0 + idx) * 3;
        float h = xr[0] * v0 + xr[1] * v1 + xr[2] * v2;
        float bs = (h - lin0) * inv_dlin;         // b* where sigmoid = 0.5
        float bF = floorf(bs);
        float e0 = exp2f((bs - bF) * d2);         // in [1, 2^20.5)
        float s0 = __builtin_amdgcn_rcpf(1.f + e0);
        float s1 = __builtin_amdgcn_rcpf(fmaf(e0, fstep, 1.f));
        int q0 = (int)(s0 * (float)SCALEI);
        int q1 = (int)(s1 * (float)SCALEI);
        int ib = (int)bF;
        int i0 = min(33, max(0, ib));
        int i1 = min(33, max(0, ib + 1));
        int i2 = min(33, max(0, ib + 2));
        atomicAdd(&hist[i0 * 32 + t], q0);
        atomicAdd(&hist[i1 * 32 + t], q1 - q0);
        atomicAdd(&hist[i2 * 32 + t], SCALEI - q1);
    }

    // ---- edge items (-): height = max over two endpoints (L2 gathers) ----
    int elo = lo > nn ? lo : nn;
    for (int idx = elo + sub; idx < hi; idx += 8) {
        int2 sd = bucket[(size_t)g * CAP + (idx - nn)];
        const float* xs = x + (size_t)sd.x * 3;
        const float* xd = x + (size_t)sd.y * 3;
        float hs = xs[0] * v0 + xs[1] * v1 + xs[2] * v2;
        float hd = xd[0] * v0 + xd[1] * v1 + xd[2] * v2;
        float h = fmaxf(hs, hd);
        float bs = (h - lin0) * inv_dlin;
        float bF = floorf(bs);
        float e0 = exp2f((bs - bF) * d2);
        float s0 = __builtin_amdgcn_rcpf(1.f + e0);
        float s1 = __builtin_amdgcn_rcpf(fmaf(e0, fstep, 1.f));
        int q0 = (int)(s0 * (float)SCALEI);
        int q1 = (int)(s1 * (float)SCALEI);
        int ib = (int)bF;
        int i0 = min(33, max(0, ib));
        int i1 = min(33, max(0, ib + 1));
        int i2 = min(33, max(0, ib + 2));
        atomicAdd(&hist[i0 * 32 + t], -q0);
        atomicAdd(&hist[i1 * 32 + t], q0 - q1);
        atomicAdd(&hist[i2 * 32 + t], q1 - SCALEI);
    }

    __syncthreads();
    // prefix over b per t-column (banks distinct across the 32 lanes), scale
    if (tid < 32) {
        int run = 0;
#pragma unroll
        for (int b = 0; b < 32; ++b) {
            run += hist[b * 32 + tid];
            colf[b * 32 + tid] = (float)run * ISCALE;
        }
    }
    __syncthreads();
    for (int c = tid; c < 1024; c += WG)
        unsafeAtomicAdd(&out[((size_t)g << 10) + c], colf[c]);
}

extern "C" void kernel_launch(void* const* d_in, const int* in_sizes, int n_in,
                              void* d_out, int out_size, void* d_ws, size_t ws_size,
                              hipStream_t stream) {
    const float* x     = (const float*)d_in[0];
    const float* v     = (const float*)d_in[1];
    const float* lin   = (const float*)d_in[2];
    const int*   edge  = (const int*)d_in[3];
    const int*   batch = (const int*)d_in[4];
    int N = in_sizes[4];
    int E = in_sizes[3] / 2;

    float* out = (float*)d_out;

    // workspace: [cursor 64][node_off 65][pad to 1024B][bucket G64*CAP*8B]
    int* cursor   = (int*)d_ws;
    int* node_off = cursor + G64;
    int2* bucket  = (int2*)((char*)d_ws + 1024);
    long long cap_ws = (long long)((ws_size - 1024) / ((size_t)G64 * sizeof(int2)));
    int CAP = (int)(cap_ws < (long long)E ? cap_ws : (long long)E);

    hipMemsetAsync(cursor, 0, G64 * sizeof(int), stream);

    k_bucket<<<(E + WG - 1) / WG, WG, 0, stream>>>(edge, batch, bucket, cursor,
                                                   node_off, out, E, N, CAP);
    dim3 grid(G64, SPLITS);
    k_acc<<<grid, WG, 0, stream>>>(x, v, bucket, lin, cursor, node_off, out, CAP);
}